// Round 5
// baseline (347.744 us; speedup 1.0000x reference)
//
#include <hip/hip_runtime.h>
#include <hip/hip_bf16.h>

#define NB 16
#define NT 512
#define ND 256
#define NH 4
#define NHD 64
#define NTAG 64

typedef short bf16x8 __attribute__((ext_vector_type(8)));
typedef float f32x4 __attribute__((ext_vector_type(4)));
union LdsVec { uint4 u; bf16x8 v; };

#define INV2PI 0.15915494309189535f

// XOR-swizzled byte offsets (guide G4): rows of 128B (Ks/Qs/Ps/Ms) and
// 1024B (Vts). XOR bits 4-6 with low row bits -> 16B-block bijection,
// same formula on 2B writes and 16B reads.
#define KSW(t, bc) ((t) * 128 + ((bc) ^ (((t) & 7) << 4)))
#define VSW(d, bc) ((d) * 1024 + ((bc) ^ (((d) & 7) << 4)))

__device__ __forceinline__ float ldf(const void* p, int isbf, long i) {
  return isbf ? __bfloat162float(((const __hip_bfloat16*)p)[i])
              : ((const float*)p)[i];
}
__device__ __forceinline__ unsigned short bfbits(float f) {
  __hip_bfloat16 h = __float2bfloat16(f);
  union { __hip_bfloat16 h; unsigned short s; } u{h};
  return u.s;
}
__device__ __forceinline__ unsigned int pack2(float a, float b) {
  return ((unsigned int)bfbits(b) << 16) | bfbits(a);
}

template <int CTRL>
__device__ __forceinline__ float dppf(float v) {
  return __int_as_float(
      __builtin_amdgcn_update_dpp(0, __float_as_int(v), CTRL, 0xF, 0xF, false));
}

// Native transcendental wrappers (no IEEE-div expansion, no scale-mul).
__device__ __forceinline__ float frcp(float x) {
#if __has_builtin(__builtin_amdgcn_rcpf)
  return __builtin_amdgcn_rcpf(x);
#else
  float r; asm("v_rcp_f32 %0, %1" : "=v"(r) : "v"(x)); return r;
#endif
}
__device__ __forceinline__ float fexp2(float x) {
#if __has_builtin(__builtin_amdgcn_exp2f)
  return __builtin_amdgcn_exp2f(x);
#else
  float r; asm("v_exp_f32 %0, %1" : "=v"(r) : "v"(x)); return r;
#endif
}
__device__ __forceinline__ float fcosr(float x) {  // input in REVOLUTIONS
#if __has_builtin(__builtin_amdgcn_cosf)
  return __builtin_amdgcn_cosf(x);
#else
  float r; asm("v_cos_f32 %0, %1" : "=v"(r) : "v"(x)); return r;
#endif
}

// Per-block dtype self-detection (block-wide; needs all threads).
__device__ __forceinline__ int detect_isbf(const void* buf, int nview) {
  __shared__ int s_big;
  if (threadIdx.x == 0) s_big = 0;
  __syncthreads();
  const __hip_bfloat16* p = (const __hip_bfloat16*)buf;
  int big = 0;
  for (int i = threadIdx.x; i < nview; i += blockDim.x) {
    float v = __bfloat162float(p[i]);
    if (fabsf(v) > 1e4f) big = 1;
  }
  if (big) atomicOr(&s_big, 1);
  __syncthreads();
  return s_big ? 0 : 1;
}

// ---------------- combine: M = WG@Wo, cvec, P prefill (4 blocks) -----------
// (Old k_qkvc z==3 branch, standalone. Must precede k_fused: Mbf + P prefill.)
__global__ __launch_bounds__(256) void k_comb(
    const void* Wo, const void* bo,
    const void* Wf, const void* Wi, const void* Wg, const void* Wo2,
    const void* bF, const void* bI, const void* bG, const void* bO,
    const void* thF, const void* thI, const void* thG, const void* thO,
    __hip_bfloat16* __restrict__ Mbf, float* __restrict__ P) {
  __shared__ float WGs[16][256];
  __shared__ float cs[16];
  int tid = threadIdx.x;
  int isbf = detect_isbf(Wo, 4096);
  for (int e = tid; e < 4096; e += 256) {
    int oi = e >> 8, j = e & 255;
    int gate = oi >> 2, w = oi & 3;
    const void* Ws = (gate == 0) ? Wf : (gate == 1) ? Wi : (gate == 2) ? Wg : Wo2;
    WGs[oi][j] = ldf(Ws, isbf, (long)w * 260 + j);
  }
  __syncthreads();
  if (tid < 64) {
    int d = blockIdx.x * 64 + tid;
    float m[16];
#pragma unroll
    for (int oi = 0; oi < 16; ++oi) m[oi] = 0.f;
#pragma unroll 4
    for (int j = 0; j < 256; ++j) {
      float wo = ldf(Wo, isbf, (long)j * 256 + d);
#pragma unroll
      for (int oi = 0; oi < 16; ++oi) m[oi] += WGs[oi][j] * wo;
    }
#pragma unroll
    for (int oi = 0; oi < 16; ++oi)
      Mbf[oi * 256 + d] = __float2bfloat16(m[oi]);
  }
  if (tid < 16) {
    int gate = tid >> 2, w = tid & 3;
    float cc = 0.f;
    for (int j = 0; j < 256; ++j) cc += WGs[tid][j] * ldf(bo, isbf, j);
    const void* bsel = (gate == 0) ? bF : (gate == 1) ? bI : (gate == 2) ? bG : bO;
    const void* tsel = (gate == 0) ? thF : (gate == 1) ? thI : (gate == 2) ? thG : thO;
    cs[tid] = (cc + ldf(bsel, isbf, w) + ldf(tsel, isbf, w)) * INV2PI;
  }
  __syncthreads();
  long pb = (long)blockIdx.x * 32768;
  for (int i = tid; i < 32768; i += 256) P[pb + i] = cs[i & 15];
}

// ---------------- fused QKV-GEMM + flash attention + P partial -------------
// R5: Q/K/V never touch HBM (was 12.6MB write + 12.6MB re-read at the
// observed ~266 GB/s regime ceiling = ~95us of the 233us total). One block =
// (bh, q-tile-pair): computes its head's full K(512x64)/V^T(64x512) from
// emb-gathered A-frags x weight B-frags (96 VGPRs), into XOR-swizzled LDS;
// then the proven barrier-free flash loop + M^T partial + P atomics.
// emb re-reads across blocks are L3-absorbed (8MB << 256MB; FETCH = HBM only).
__global__ __launch_bounds__(256) void k_fused(
    const int* __restrict__ sent, const void* emb,
    const void* Wq, const void* Wk, const void* Wv,
    const void* bq, const void* bk, const void* bv,
    const __hip_bfloat16* __restrict__ Mbf, float* __restrict__ P) {
  __shared__ __align__(16) unsigned char Ks[512 * 128];    // 64KB  K[t][d]
  __shared__ __align__(16) unsigned char Vts[64 * 1024];   // 64KB  V^T[d][t]
  __shared__ __align__(16) unsigned char Qs[2 * 64 * 128]; // 16KB  Q tiles
  __shared__ __align__(16) unsigned char Ps[64 * 128];     // 8KB   P / AO
  __shared__ __align__(16) unsigned char Ms[16 * 128];     // 2KB   M head slice
  __shared__ int stok[512];                                // 2KB

  int tid = threadIdx.x;
  int bh = blockIdx.x;                 // 0..63
  int batch = bh >> 2, head = bh & 3;
  int qt0 = blockIdx.y * 2;            // q-tiles qt0, qt0+1
  int wave = tid >> 6, lane = tid & 63, li = lane & 15, quad = lane >> 4;

  int isbf = detect_isbf(Wq, 1024);

  // ---- stage tokens + M slice ----
  for (int i = tid; i < 512; i += 256) stok[i] = sent[batch * 512 + i];
  if (tid < 128) {
    int r = tid >> 3, c8 = (tid & 7) * 8;
    *(uint4*)(Ms + KSW(r, c8 * 2)) =
        *(const uint4*)&Mbf[r * 256 + head * 64 + c8];
  }

  // ---- weight B-fragments -> registers (lane l: row head*64+w*16+(l&15),
  //      k-slice (l>>4)*8 within each 32-wide k0 step) ----
  uint4 wqf[8], wkf[8], wvf[8];
  {
    long row = (long)(head * 64 + wave * 16 + li) * 256;
#pragma unroll
    for (int k0 = 0; k0 < 8; ++k0) {
      long off = row + k0 * 32 + quad * 8;
      if (isbf) {
        wqf[k0] = *(const uint4*)((const __hip_bfloat16*)Wq + off);
        wkf[k0] = *(const uint4*)((const __hip_bfloat16*)Wk + off);
        wvf[k0] = *(const uint4*)((const __hip_bfloat16*)Wv + off);
      } else {
        const float* pq = (const float*)Wq + off;
        const float* pk = (const float*)Wk + off;
        const float* pv = (const float*)Wv + off;
        float4 lo, hi; uint4 pkk;
        lo = *(const float4*)pq; hi = *(const float4*)(pq + 4);
        pkk.x = pack2(lo.x, lo.y); pkk.y = pack2(lo.z, lo.w);
        pkk.z = pack2(hi.x, hi.y); pkk.w = pack2(hi.z, hi.w);
        wqf[k0] = pkk;
        lo = *(const float4*)pk; hi = *(const float4*)(pk + 4);
        pkk.x = pack2(lo.x, lo.y); pkk.y = pack2(lo.z, lo.w);
        pkk.z = pack2(hi.x, hi.y); pkk.w = pack2(hi.z, hi.w);
        wkf[k0] = pkk;
        lo = *(const float4*)pv; hi = *(const float4*)(pv + 4);
        pkk.x = pack2(lo.x, lo.y); pkk.y = pack2(lo.z, lo.w);
        pkk.z = pack2(hi.x, hi.y); pkk.w = pack2(hi.z, hi.w);
        wvf[k0] = pkk;
      }
    }
  }
  int mycol = head * 64 + wave * 16 + li;
  float kb = ldf(bk, isbf, mycol);
  float vb = ldf(bv, isbf, mycol);
  float qb = ldf(bq, isbf, mycol);
  __syncthreads();   // stok/Ms visible

  // ---- K/V(/Q) GEMM, 8 chunks of 64 tokens ----
#pragma unroll 1
  for (int c = 0; c < 8; ++c) {
    int tok[4];
#pragma unroll
    for (int mt = 0; mt < 4; ++mt) tok[mt] = stok[c * 64 + mt * 16 + li];
    int isq = (c == qt0) ? 0 : (c == qt0 + 1) ? 1 : -1;  // block-uniform
    f32x4 ka[4], va[4], qa[4];
#pragma unroll
    for (int mt = 0; mt < 4; ++mt) {
      ka[mt] = (f32x4){0.f, 0.f, 0.f, 0.f};
      va[mt] = (f32x4){0.f, 0.f, 0.f, 0.f};
      qa[mt] = (f32x4){0.f, 0.f, 0.f, 0.f};
    }
#pragma unroll
    for (int k0 = 0; k0 < 8; ++k0) {
      LdsVec a[4];
#pragma unroll
      for (int mt = 0; mt < 4; ++mt) {
        long off = (long)tok[mt] * 256 + k0 * 32 + quad * 8;
        if (isbf) {
          a[mt].u = *(const uint4*)((const __hip_bfloat16*)emb + off);
        } else {
          const float* pe = (const float*)emb + off;
          float4 lo = *(const float4*)pe;
          float4 hi = *(const float4*)(pe + 4);
          a[mt].u.x = pack2(lo.x, lo.y); a[mt].u.y = pack2(lo.z, lo.w);
          a[mt].u.z = pack2(hi.x, hi.y); a[mt].u.w = pack2(hi.z, hi.w);
        }
      }
#pragma unroll
      for (int mt = 0; mt < 4; ++mt) {
        LdsVec bb;
        bb.u = wkf[k0];
        ka[mt] = __builtin_amdgcn_mfma_f32_16x16x32_bf16(a[mt].v, bb.v, ka[mt], 0, 0, 0);
        bb.u = wvf[k0];
        va[mt] = __builtin_amdgcn_mfma_f32_16x16x32_bf16(a[mt].v, bb.v, va[mt], 0, 0, 0);
        if (isq >= 0) {
          bb.u = wqf[k0];
          qa[mt] = __builtin_amdgcn_mfma_f32_16x16x32_bf16(a[mt].v, bb.v, qa[mt], 0, 0, 0);
        }
      }
    }
    // C-layout (row = mt*16+quad*4+reg, col = wave*16+li) -> swizzled LDS
    int d = wave * 16 + li;
#pragma unroll
    for (int mt = 0; mt < 4; ++mt) {
#pragma unroll
      for (int reg = 0; reg < 4; ++reg) {
        int t = c * 64 + mt * 16 + quad * 4 + reg;
        *(unsigned short*)(Ks + KSW(t, 2 * d)) = bfbits(ka[mt][reg] + kb);
        *(unsigned short*)(Vts + VSW(d, 2 * t)) = bfbits(va[mt][reg] + vb);
        if (isq >= 0) {
          int tq = mt * 16 + quad * 4 + reg;
          *(unsigned short*)(Qs + isq * 8192 + KSW(tq, 2 * d)) =
              bfbits(qa[mt][reg] + qb);
        }
      }
    }
  }
  __syncthreads();   // K/V/Q cross-wave visible; barrier-free from here on

  // ---- flash attention per q-tile (all Ps/Qs row accesses wave-private) ----
  long pbase = (long)(batch >> 2) * 32768 + (batch & 3) * 16 + li;
#pragma unroll 1
  for (int qi = 0; qi < 2; ++qi) {
    const unsigned char* Qsi = Qs + qi * 8192;
    f32x4 accO[4];
    float mrow[4], lrow[4];
#pragma unroll
    for (int i = 0; i < 4; ++i) {
      accO[i] = (f32x4){0.f, 0.f, 0.f, 0.f};
      mrow[i] = -1e30f; lrow[i] = 0.f;
    }
#pragma unroll 1
    for (int kt = 0; kt < 8; ++kt) {
      f32x4 s[4];
#pragma unroll
      for (int nb = 0; nb < 4; ++nb) s[nb] = (f32x4){0.f, 0.f, 0.f, 0.f};
#pragma unroll
      for (int nb = 0; nb < 4; ++nb)
#pragma unroll
        for (int kc = 0; kc < 2; ++kc) {
          LdsVec a, b;
          a.u = *(const uint4*)(Qsi + KSW(wave * 16 + li, kc * 64 + quad * 16));
          int krow = kt * 64 + nb * 16 + li;
          b.u = *(const uint4*)(Ks + KSW(krow, kc * 64 + quad * 16));
          s[nb] = __builtin_amdgcn_mfma_f32_16x16x32_bf16(a.v, b.v, s[nb], 0, 0, 0);
        }
#pragma unroll
      for (int nb = 0; nb < 4; ++nb) s[nb] *= 0.125f;

#pragma unroll
      for (int reg = 0; reg < 4; ++reg) {
        float rm = fmaxf(fmaxf(s[0][reg], s[1][reg]), fmaxf(s[2][reg], s[3][reg]));
        rm = fmaxf(rm, __shfl_xor(rm, 1));
        rm = fmaxf(rm, __shfl_xor(rm, 2));
        rm = fmaxf(rm, __shfl_xor(rm, 4));
        rm = fmaxf(rm, __shfl_xor(rm, 8));
        float mnew = fmaxf(mrow[reg], rm);
        float alpha = __expf(mrow[reg] - mnew);
        mrow[reg] = mnew;
        float psum = 0.f;
        int pr = wave * 16 + quad * 4 + reg;
#pragma unroll
        for (int nb = 0; nb < 4; ++nb) {
          float p = __expf(s[nb][reg] - mnew);
          psum += p;
          *(unsigned short*)(Ps + KSW(pr, 2 * (nb * 16 + li))) = bfbits(p);
        }
        psum += __shfl_xor(psum, 1);
        psum += __shfl_xor(psum, 2);
        psum += __shfl_xor(psum, 4);
        psum += __shfl_xor(psum, 8);
        lrow[reg] = lrow[reg] * alpha + psum;
#pragma unroll
        for (int db = 0; db < 4; ++db) accO[db][reg] *= alpha;
      }

#pragma unroll
      for (int db = 0; db < 4; ++db)
#pragma unroll
        for (int kc = 0; kc < 2; ++kc) {
          LdsVec a, b;
          a.u = *(const uint4*)(Ps + KSW(wave * 16 + li, kc * 64 + quad * 16));
          b.u = *(const uint4*)(Vts + VSW(db * 16 + li,
                                          kt * 128 + kc * 64 + quad * 16));
          accO[db] = __builtin_amdgcn_mfma_f32_16x16x32_bf16(a.v, b.v, accO[db], 0, 0, 0);
        }
    }

    // epilogue: normalized AO -> Ps (C->A transform), D = AO @ M_h^T, P atomics
#pragma unroll
    for (int reg = 0; reg < 4; ++reg) {
      float inv = frcp(lrow[reg]);
      int pr = wave * 16 + quad * 4 + reg;
#pragma unroll
      for (int db = 0; db < 4; ++db)
        *(unsigned short*)(Ps + KSW(pr, 2 * (db * 16 + li))) =
            bfbits(accO[db][reg] * inv);
    }
    f32x4 pacc = (f32x4){0.f, 0.f, 0.f, 0.f};
#pragma unroll
    for (int kc = 0; kc < 2; ++kc) {
      LdsVec a, b;
      a.u = *(const uint4*)(Ps + KSW(wave * 16 + li, kc * 64 + quad * 16));
      b.u = *(const uint4*)(Ms + KSW(li, kc * 64 + quad * 16));
      pacc = __builtin_amdgcn_mfma_f32_16x16x32_bf16(a.v, b.v, pacc, 0, 0, 0);
    }
#pragma unroll
    for (int reg = 0; reg < 4; ++reg) {
      int t = (qt0 + qi) * 64 + wave * 16 + quad * 4 + reg;
      atomicAdd(&P[pbase + (long)t * 64], pacc[reg] * INV2PI);  // revolutions
    }
  }
}

// ---------------- chunked fixed-point scan (block-Jacobi over time) --------
// Weak recurrent coupling -> 32 chunks x 16 steps, 4 sweeps, exact-to-bf16.
// Serial depth 512 -> 64. (R3: 196 -> <20 us, verified.)
#define SWEEPS 4
#define CHUNK 16
#define NCH 32

template <bool DIRB>
__device__ __forceinline__ void scan_sweeps(
    const float* __restrict__ Pb, float* __restrict__ HS, int b,
    int c, int G, int w,
    float rr0, float rr1, float rr2, float rr3,
    float kk, float e1, float mkm1,
    int s0, int s1, int s2, int s3,
    float (*bH)[NCH + 1][4], float (*bC)[NCH + 1][4],
    float* __restrict__ hsb) {
  float pcv[CHUNK];
#pragma unroll
  for (int j = 0; j < CHUNK; ++j)
    pcv[j] = Pb[(long)(c * CHUNK + j) * 64];

#pragma unroll 1
  for (int s = 0; s < SWEEPS; ++s) {
    int rd = s & 1, wr = rd ^ 1;
    float h0 = bH[rd][c][0], h1 = bH[rd][c][1];
    float h2 = bH[rd][c][2], h3 = bH[rd][c][3];
    float cx = bC[rd][c][w];
    float hx = 0.f;
#pragma unroll
    for (int u = 0; u < CHUNK; ++u) {
      float pc = pcv[u];
      float d01 = __builtin_fmaf(rr1, h1, __builtin_fmaf(rr0, h0, pc));
      float d23 = __builtin_fmaf(rr3, h3, rr2 * h2);
      float a = d01 + d23;                 // revolutions
      float cth = fcosr(a);
      float c0 = dppf<0x00>(cth), c1 = dppf<0x55>(cth);
      float c2 = dppf<0xAA>(cth), c3 = dppf<0xFF>(cth);
      float p01 = c0 * c1, z23 = c2 * c3;
      float v = (w == 0) ? c1 * z23 : (w == 1) ? p01
              : (w == 2) ? p01 * c2 : p01 * z23;
      float val = __builtin_fmaf(kk, frcp(1.f + fexp2(e1 * v)), mkm1);
      float ra = dppf<0x124>(val);
      float rb = dppf<0x128>(val);
      float rc = dppf<0x12C>(val);
      float rot1 = DIRB ? ra : rc;
      float rot3 = DIRB ? rc : ra;
      float f = (s0 == 0) ? val : (s0 == 1) ? rot1 : (s0 == 2) ? rb : rot3;
      float i = (s1 == 0) ? val : (s1 == 1) ? rot1 : (s1 == 2) ? rb : rot3;
      float g = (s2 == 0) ? val : (s2 == 1) ? rot1 : (s2 == 2) ? rb : rot3;
      float o = (s3 == 0) ? val : (s3 == 1) ? rot1 : (s3 == 2) ? rb : rot3;
      cx = __builtin_fmaf(f, cx, i * g);
      float rt = frcp(1.f + fexp2(-2.88539008f * cx));
      hx = __builtin_fmaf(o + o, rt, -o);
      h0 = dppf<0x00>(hx); h1 = dppf<0x55>(hx);
      h2 = dppf<0xAA>(hx); h3 = dppf<0xFF>(hx);
      if (G == 0) hsb[(c * CHUNK + u) * 4 + w] = hx;
    }
    if (G == 0) {
      bH[wr][c + 1][w] = hx;
      bC[wr][c + 1][w] = cx;
    }
    __syncthreads();
  }
  int tid = threadIdx.x;
  *(float4*)&HS[tid * 64 + b * 4] = *(const float4*)&hsb[tid * 4];
}

__global__ __launch_bounds__(512) void k_scan(const float* __restrict__ P,
                                              const void* Wf, const void* Wi,
                                              const void* Wg, const void* Wo2,
                                              float* __restrict__ HS) {
  __shared__ float bH[2][NCH + 1][4];
  __shared__ float bC[2][NCH + 1][4];
  __shared__ __align__(16) float hsb[512 * 4];
  int tid = threadIdx.x;
  int b = blockIdx.x;            // batch 0..15
  int c = tid >> 4;              // chunk 0..31
  int l16 = tid & 15;
  int G = l16 >> 2, w = l16 & 3;
  int lane = tid & 63;

  if (tid < 2 * (NCH + 1) * 4) {
    ((float*)bH)[tid] = 0.f;
    ((float*)bC)[tid] = 0.f;
  }

  const __hip_bfloat16* pw = (const __hip_bfloat16*)Wf;
  int big = 0;
  for (int i = lane; i < 1040; i += 64) {
    float v = __bfloat162float(pw[i]);
    if (fabsf(v) > 1e4f) big = 1;
  }
  int isbf = (__ballot(big) == 0ULL) ? 1 : 0;
  int got = __builtin_amdgcn_update_dpp(0, lane, 0x124, 0xF, 0xF, false); // row_ror:4
  int dir = __shfl((got == 9) ? 1 : 0, 5);
  const void* Wsel = (G == 0) ? Wf : (G == 1) ? Wi : (G == 2) ? Wg : Wo2;
  float rr0 = ldf(Wsel, isbf, (long)w * 260 + 256 + 0) * INV2PI;
  float rr1 = ldf(Wsel, isbf, (long)w * 260 + 256 + 1) * INV2PI;
  float rr2 = ldf(Wsel, isbf, (long)w * 260 + 256 + 2) * INV2PI;
  float rr3 = ldf(Wsel, isbf, (long)w * 260 + 256 + 3) * INV2PI;
  float kk = (G == 2) ? 2.f : 1.f;
  float e1 = -kk * 1.44269504f;
  float mkm1 = 1.f - kk;
  int s0 = (0 - G) & 3, s1 = (1 - G) & 3, s2 = (2 - G) & 3, s3 = (3 - G) & 3;

  const float* Pb = P + (long)(b >> 2) * 32768 + (b & 3) * 16 + l16;
  __syncthreads();  // boundary zero-init visible to all

  if (dir)
    scan_sweeps<true>(Pb, HS, b, c, G, w, rr0, rr1, rr2, rr3,
                      kk, e1, mkm1, s0, s1, s2, s3, bH, bC, hsb);
  else
    scan_sweeps<false>(Pb, HS, b, c, G, w, rr0, rr1, rr2, rr3,
                       kk, e1, mkm1, s0, s1, s2, s3, bH, bC, hsb);
}

// ---------------- logits + log_softmax (4 rows/block) ----------------
__global__ __launch_bounds__(256) void k_final(const float* __restrict__ HS,
                                               const void* Wt, const void* Bt,
                                               void* outp) {
  int isbf = detect_isbf(Wt, 256);
  int wave = threadIdx.x >> 6, j = threadIdx.x & 63;
  int r = blockIdx.x * 4 + wave;
  int b = r >> 9, t = r & 511;
  const float* h = &HS[t * 64 + b * 4];
  float h0 = h[0], h1 = h[1], h2 = h[2], h3 = h[3];
  float lg = ldf(Bt, isbf, j)
           + h0 * ldf(Wt, isbf, (long)j * 4 + 0)
           + h1 * ldf(Wt, isbf, (long)j * 4 + 1)
           + h2 * ldf(Wt, isbf, (long)j * 4 + 2)
           + h3 * ldf(Wt, isbf, (long)j * 4 + 3);
  float mx = lg;
#pragma unroll
  for (int off = 1; off < 64; off <<= 1) mx = fmaxf(mx, __shfl_xor(mx, off));
  float e = __expf(lg - mx);
  float ssum = e;
#pragma unroll
  for (int off = 1; off < 64; off <<= 1) ssum += __shfl_xor(ssum, off);
  float res = lg - mx - __logf(ssum);
  long oidx = (long)r * 64 + j;
  if (isbf) ((__hip_bfloat16*)outp)[oidx] = __float2bfloat16(res);
  else ((float*)outp)[oidx] = res;
}

extern "C" void kernel_launch(void* const* d_in, const int* in_sizes, int n_in,
                              void* d_out, int out_size, void* d_ws, size_t ws_size,
                              hipStream_t stream) {
  const int* sent = (const int*)d_in[0];
  const void* emb = d_in[1];
  const void* Wq = d_in[2];  const void* bq = d_in[3];
  const void* Wk = d_in[4];  const void* bk = d_in[5];
  const void* Wv = d_in[6];  const void* bv = d_in[7];
  const void* Wo = d_in[8];  const void* bo = d_in[9];
  const void* Wf = d_in[10]; const void* bF = d_in[11]; const void* thF = d_in[12];
  const void* Wi = d_in[13]; const void* bI = d_in[14]; const void* thI = d_in[15];
  const void* Wg = d_in[16]; const void* bG = d_in[17]; const void* thG = d_in[18];
  const void* Wo2 = d_in[19]; const void* bO = d_in[20]; const void* thO = d_in[21];
  const void* Wt = d_in[22]; const void* Bt = d_in[23];

  float* base = (float*)((char*)d_ws + 256);
  __hip_bfloat16* Mbf = (__hip_bfloat16*)base;   // 16x256 bf16
  float* Pp = base + 4096;                       // 131072 f32 (4 x 32768)
  float* HS = Pp + 131072;                       // 32768 f32

  k_comb<<<4, 256, 0, stream>>>(Wo, bo, Wf, Wi, Wg, Wo2, bF, bI, bG, bO,
                                thF, thI, thG, thO, Mbf, Pp);
  dim3 gf(64, 4, 1);
  k_fused<<<gf, 256, 0, stream>>>(sent, emb, Wq, Wk, Wv, bq, bk, bv, Mbf, Pp);
  k_scan<<<16, 512, 0, stream>>>(Pp, Wf, Wi, Wg, Wo2, HS);
  k_final<<<2048, 256, 0, stream>>>(HS, Wt, Bt, d_out);
}

// Round 6
// 231.895 us; speedup vs baseline: 1.4996x; 1.4996x over previous
//
#include <hip/hip_runtime.h>
#include <hip/hip_bf16.h>

#define NB 16
#define NT 512
#define ND 256
#define NH 4
#define NHD 64
#define NTAG 64

typedef short bf16x8 __attribute__((ext_vector_type(8)));
typedef float f32x4 __attribute__((ext_vector_type(4)));
union LdsVec { uint4 u; bf16x8 v; };

#define INV2PI 0.15915494309189535f

__device__ __forceinline__ float ldf(const void* p, int isbf, long i) {
  return isbf ? __bfloat162float(((const __hip_bfloat16*)p)[i])
              : ((const float*)p)[i];
}
__device__ __forceinline__ unsigned short bfbits(float f) {
  __hip_bfloat16 h = __float2bfloat16(f);
  union { __hip_bfloat16 h; unsigned short s; } u{h};
  return u.s;
}
__device__ __forceinline__ unsigned int pack2(float a, float b) {
  return ((unsigned int)bfbits(b) << 16) | bfbits(a);
}

template <int CTRL>
__device__ __forceinline__ float dppf(float v) {
  return __int_as_float(
      __builtin_amdgcn_update_dpp(0, __float_as_int(v), CTRL, 0xF, 0xF, false));
}

// Native transcendental wrappers (no IEEE-div expansion, no scale-mul).
__device__ __forceinline__ float frcp(float x) {
#if __has_builtin(__builtin_amdgcn_rcpf)
  return __builtin_amdgcn_rcpf(x);
#else
  float r; asm("v_rcp_f32 %0, %1" : "=v"(r) : "v"(x)); return r;
#endif
}
__device__ __forceinline__ float fexp2(float x) {
#if __has_builtin(__builtin_amdgcn_exp2f)
  return __builtin_amdgcn_exp2f(x);
#else
  float r; asm("v_exp_f32 %0, %1" : "=v"(r) : "v"(x)); return r;
#endif
}
__device__ __forceinline__ float fcosr(float x) {  // input in REVOLUTIONS
#if __has_builtin(__builtin_amdgcn_cosf)
  return __builtin_amdgcn_cosf(x);
#else
  float r; asm("v_cos_f32 %0, %1" : "=v"(r) : "v"(x)); return r;
#endif
}

// Per-block dtype self-detection (block-wide; needs all threads).
__device__ __forceinline__ int detect_isbf(const void* buf, int nview) {
  __shared__ int s_big;
  if (threadIdx.x == 0) s_big = 0;
  __syncthreads();
  const __hip_bfloat16* p = (const __hip_bfloat16*)buf;
  int big = 0;
  for (int i = threadIdx.x; i < nview; i += blockDim.x) {
    float v = __bfloat162float(p[i]);
    if (fabsf(v) > 1e4f) big = 1;
  }
  if (big) atomicOr(&s_big, 1);
  __syncthreads();
  return s_big ? 0 : 1;
}

// ---------------- QKV GEMM (z<3) + combine/P-init (z==3), one launch -------
// R4 structure (proven 77us): 64 rows x full 256 cols, A staged once,
// B wave-private, zero K-loop barriers, pipelined B loads.
// R6 delta: COALESCED EPILOGUE. The old epilogue issued 64 scalar 2B stores
// per thread (~16K store requests/block, the block's largest request
// population under the request-rate model). Now: C-tile -> LDS (row-major
// for Q/K, transposed for V^T), one barrier, then 8 x 16B dwordx4 stores
// per thread, streaming-contiguous.
#define AST 264
#define BST 40
__global__ __launch_bounds__(256) void k_qkvc(
    const int* __restrict__ sent, const void* emb,
    const void* Wq, const void* Wk, const void* Wv,
    const void* bq, const void* bk, const void* bv,
    const void* Wo, const void* bo,
    const void* Wf, const void* Wi, const void* Wg, const void* Wo2,
    const void* bF, const void* bI, const void* bG, const void* bO,
    const void* thF, const void* thI, const void* thG, const void* thO,
    __hip_bfloat16* Qbf, __hip_bfloat16* Kbf, __hip_bfloat16* Vtbf,
    __hip_bfloat16* __restrict__ Mbf, float* __restrict__ P) {
  // one shared pool, carved: AS = 64x264 shorts, BS = 4x64x40 shorts.
  // epilogue reuses the pool: z<2 row-stage 64x264, z==2 transp 256x72.
  __shared__ __align__(16) unsigned short SH[64 * AST + 4 * 64 * BST];
  unsigned short* AS = SH;
  unsigned short* BS = SH + 64 * AST;
  int z = blockIdx.z;
  int tid = threadIdx.x;

  if (z == 3) {
    if (blockIdx.x >= 4) return;
    float (*WGs)[256] = (float(*)[256])SH;     // 16KB overlay
    float* cs = (float*)BS;                    // 64B overlay
    int isbf = detect_isbf(Wo, 4096);
    for (int e = tid; e < 4096; e += 256) {
      int oi = e >> 8, j = e & 255;
      int gate = oi >> 2, w = oi & 3;
      const void* Ws = (gate == 0) ? Wf : (gate == 1) ? Wi : (gate == 2) ? Wg : Wo2;
      WGs[oi][j] = ldf(Ws, isbf, (long)w * 260 + j);
    }
    __syncthreads();
    if (tid < 64) {
      int d = blockIdx.x * 64 + tid;
      float m[16];
#pragma unroll
      for (int oi = 0; oi < 16; ++oi) m[oi] = 0.f;
#pragma unroll 4
      for (int j = 0; j < 256; ++j) {
        float wo = ldf(Wo, isbf, (long)j * 256 + d);
#pragma unroll
        for (int oi = 0; oi < 16; ++oi) m[oi] += WGs[oi][j] * wo;
      }
#pragma unroll
      for (int oi = 0; oi < 16; ++oi)
        Mbf[oi * 256 + d] = __float2bfloat16(m[oi]);
    }
    if (tid < 16) {
      int gate = tid >> 2, w = tid & 3;
      float cc = 0.f;
      for (int j = 0; j < 256; ++j) cc += WGs[tid][j] * ldf(bo, isbf, j);
      const void* bsel = (gate == 0) ? bF : (gate == 1) ? bI : (gate == 2) ? bG : bO;
      const void* tsel = (gate == 0) ? thF : (gate == 1) ? thI : (gate == 2) ? thG : thO;
      cs[tid] = (cc + ldf(bsel, isbf, w) + ldf(tsel, isbf, w)) * INV2PI;
    }
    __syncthreads();
    long pb = (long)blockIdx.x * 32768;
    for (int i = tid; i < 32768; i += 256) P[pb + i] = cs[i & 15];
    return;
  }

  const void* W = (z == 0) ? Wq : (z == 1) ? Wk : Wv;
  const void* Bb = (z == 0) ? bq : (z == 1) ? bk : bv;
  __hip_bfloat16* O = (z == 0) ? Qbf : (z == 1) ? Kbf : Vtbf;
  int isbf = detect_isbf(W, 1024);

  int rowbase = blockIdx.x * 64;
  int wave = tid >> 6, lane = tid & 63;
  int li = lane & 15, quad = lane >> 4;
  int colbase = wave * 64;
  unsigned short* Bw = &BS[wave * 64 * BST];

  const float* Wf32 = (const float*)W;
  const __hip_bfloat16* Wb16 = (const __hip_bfloat16*)W;
  long wrow = (long)(colbase + lane) * 256;

  // ---- issue B(k0=0) prefetch first (in flight during A staging) ----
  float4 bf[8];
  uint4 bb4[4];
  if (isbf) {
#pragma unroll
    for (int j = 0; j < 4; ++j) bb4[j] = *(const uint4*)&Wb16[wrow + j * 8];
  } else {
#pragma unroll
    for (int j = 0; j < 8; ++j) bf[j] = *(const float4*)&Wf32[wrow + j * 4];
  }

  // ---- stage A (64 rows x 256 cols, one shot) ----
  {
    int srow = tid >> 2;
    int sc = (tid & 3) * 64;
    long tok = (long)sent[rowbase + srow];
    if (isbf) {
      const __hip_bfloat16* eb = (const __hip_bfloat16*)emb + tok * 256 + sc;
#pragma unroll
      for (int j = 0; j < 8; ++j)
        *(uint4*)&AS[srow * AST + sc + j * 8] = *(const uint4*)&eb[j * 8];
    } else {
      const float* ef = (const float*)emb + tok * 256 + sc;
#pragma unroll
      for (int j = 0; j < 8; ++j) {
        float4 lo = *(const float4*)&ef[j * 8];
        float4 hi = *(const float4*)&ef[j * 8 + 4];
        uint4 pk;
        pk.x = pack2(lo.x, lo.y); pk.y = pack2(lo.z, lo.w);
        pk.z = pack2(hi.x, hi.y); pk.w = pack2(hi.z, hi.w);
        *(uint4*)&AS[srow * AST + sc + j * 8] = pk;
      }
    }
  }
  __syncthreads();

  f32x4 acc[4][4];
#pragma unroll
  for (int mt = 0; mt < 4; ++mt)
#pragma unroll
    for (int nt = 0; nt < 4; ++nt) acc[mt][nt] = (f32x4){0.f, 0.f, 0.f, 0.f};

#pragma unroll
  for (int k0 = 0; k0 < 256; k0 += 32) {
    if (isbf) {
#pragma unroll
      for (int j = 0; j < 4; ++j)
        *(uint4*)&Bw[lane * BST + j * 8] = bb4[j];
    } else {
#pragma unroll
      for (int j = 0; j < 4; ++j) {
        uint4 pk;
        pk.x = pack2(bf[2 * j].x, bf[2 * j].y);
        pk.y = pack2(bf[2 * j].z, bf[2 * j].w);
        pk.z = pack2(bf[2 * j + 1].x, bf[2 * j + 1].y);
        pk.w = pack2(bf[2 * j + 1].z, bf[2 * j + 1].w);
        *(uint4*)&Bw[lane * BST + j * 8] = pk;
      }
    }
    if (k0 < 224) {
      if (isbf) {
#pragma unroll
        for (int j = 0; j < 4; ++j)
          bb4[j] = *(const uint4*)&Wb16[wrow + k0 + 32 + j * 8];
      } else {
#pragma unroll
        for (int j = 0; j < 8; ++j)
          bf[j] = *(const float4*)&Wf32[wrow + k0 + 32 + j * 4];
      }
    }
    LdsVec a[4], b[4];
#pragma unroll
    for (int mt = 0; mt < 4; ++mt)
      a[mt].u = *(const uint4*)&AS[(mt * 16 + li) * AST + k0 + quad * 8];
#pragma unroll
    for (int nt = 0; nt < 4; ++nt)
      b[nt].u = *(const uint4*)&Bw[(nt * 16 + li) * BST + quad * 8];
#pragma unroll
    for (int mt = 0; mt < 4; ++mt)
#pragma unroll
      for (int nt = 0; nt < 4; ++nt)
        acc[mt][nt] = __builtin_amdgcn_mfma_f32_16x16x32_bf16(
            a[mt].v, b[nt].v, acc[mt][nt], 0, 0, 0);
  }

  // ---- coalesced epilogue: C -> LDS -> 16B global stores ----
  __syncthreads();   // all waves done reading AS/BS before overwrite
  if (z == 2) {
    // transposed stage: SH[col*72 + rowl]  (256 x 72 shorts <= pool)
#pragma unroll
    for (int nt = 0; nt < 4; ++nt) {
      int col = colbase + nt * 16 + li;
      float bias = ldf(Bb, isbf, col);
#pragma unroll
      for (int mt = 0; mt < 4; ++mt)
#pragma unroll
        for (int reg = 0; reg < 4; ++reg)
          SH[col * 72 + mt * 16 + quad * 4 + reg] =
              bfbits(acc[mt][nt][reg] + bias);
    }
  } else {
    // row stage: SH[rowl*264 + col]
#pragma unroll
    for (int nt = 0; nt < 4; ++nt) {
      int col = colbase + nt * 16 + li;
      float bias = ldf(Bb, isbf, col);
#pragma unroll
      for (int mt = 0; mt < 4; ++mt)
#pragma unroll
        for (int reg = 0; reg < 4; ++reg)
          SH[(mt * 16 + quad * 4 + reg) * AST + col] =
              bfbits(acc[mt][nt][reg] + bias);
    }
  }
  __syncthreads();
  int bb2 = blockIdx.x >> 3, ttb = (blockIdx.x & 7) * 64;
  if (z == 2) {
    // V^T [bh][hd][t]: per (h,hd) row, 64 contiguous t
#pragma unroll
    for (int j = 0; j < 8; ++j) {
      int e = tid + j * 256;             // 0..2047
      int hdcol = e >> 3, c8 = (e & 7) * 8;
      uint4 v = *(const uint4*)&SH[hdcol * 72 + c8];
      *(uint4*)((__hip_bfloat16*)O +
                ((long)(bb2 * 4 + (hdcol >> 6)) * 64 + (hdcol & 63)) * 512 +
                ttb + c8) = v;
    }
  } else {
    // Q/K [bh][t][hd]
#pragma unroll
    for (int j = 0; j < 8; ++j) {
      int e = tid + j * 256;             // 0..2047
      int row = e >> 5, c8e = (e & 31) * 8;
      int h = c8e >> 6, hd = c8e & 63;
      uint4 v = *(const uint4*)&SH[row * AST + c8e];
      *(uint4*)((__hip_bfloat16*)O +
                ((long)(bb2 * 4 + h) * 512 + ttb + row) * 64 + hd) = v;
    }
  }
}

// ---------------- MFMA flash attention + fused P partial ----------------
#define LSTR 72
__global__ __launch_bounds__(256) void k_attn(const __hip_bfloat16* __restrict__ Qg,
                                              const __hip_bfloat16* __restrict__ Kg,
                                              const __hip_bfloat16* __restrict__ Vtg,
                                              const __hip_bfloat16* __restrict__ Mbf,
                                              float* __restrict__ P) {
  __shared__ __align__(16) unsigned short Qs[64 * LSTR];
  __shared__ __align__(16) unsigned short Ks[64 * LSTR];
  __shared__ __align__(16) unsigned short Vts[64 * LSTR];
  __shared__ __align__(16) unsigned short Ps[64 * LSTR];
  int tid = threadIdx.x;
  int bh = blockIdx.x, qt = blockIdx.y;
  int wave = tid >> 6, lane = tid & 63, li = lane & 15, quad = lane >> 4;

  const __hip_bfloat16* Qb = Qg + ((long)bh * 512 + qt * 64) * 64;
#pragma unroll
  for (int c = 0; c < 2; ++c) {
    int idx = tid + c * 256;
    int r = idx >> 3, c8 = (idx & 7) * 8;
    *(uint4*)&Qs[r * LSTR + c8] = *(const uint4*)&Qb[(long)r * 64 + c8];
  }

  f32x4 accO[4];
  float mrow[4], lrow[4];
#pragma unroll
  for (int i = 0; i < 4; ++i) {
    accO[i] = (f32x4){0.f, 0.f, 0.f, 0.f};
    mrow[i] = -1e30f; lrow[i] = 0.f;
  }

  for (int kt = 0; kt < 8; ++kt) {
    __syncthreads();
    const __hip_bfloat16* Kb = Kg + ((long)bh * 512 + kt * 64) * 64;
#pragma unroll
    for (int c = 0; c < 2; ++c) {
      int idx = tid + c * 256;
      int r = idx >> 3, c8 = (idx & 7) * 8;
      *(uint4*)&Ks[r * LSTR + c8] = *(const uint4*)&Kb[(long)r * 64 + c8];
      *(uint4*)&Vts[r * LSTR + c8] =
          *(const uint4*)&Vtg[((long)bh * 64 + r) * 512 + kt * 64 + c8];
    }
    __syncthreads();

    f32x4 s[4];
#pragma unroll
    for (int nb = 0; nb < 4; ++nb) s[nb] = (f32x4){0.f, 0.f, 0.f, 0.f};
#pragma unroll
    for (int nb = 0; nb < 4; ++nb)
#pragma unroll
      for (int kc = 0; kc < 2; ++kc) {
        LdsVec a, b;
        a.u = *(const uint4*)&Qs[(wave * 16 + li) * LSTR + kc * 32 + quad * 8];
        b.u = *(const uint4*)&Ks[(nb * 16 + li) * LSTR + kc * 32 + quad * 8];
        s[nb] = __builtin_amdgcn_mfma_f32_16x16x32_bf16(a.v, b.v, s[nb], 0, 0, 0);
      }
#pragma unroll
    for (int nb = 0; nb < 4; ++nb) s[nb] *= 0.125f;

#pragma unroll
    for (int reg = 0; reg < 4; ++reg) {
      float rm = fmaxf(fmaxf(s[0][reg], s[1][reg]), fmaxf(s[2][reg], s[3][reg]));
      rm = fmaxf(rm, __shfl_xor(rm, 1));
      rm = fmaxf(rm, __shfl_xor(rm, 2));
      rm = fmaxf(rm, __shfl_xor(rm, 4));
      rm = fmaxf(rm, __shfl_xor(rm, 8));
      float mnew = fmaxf(mrow[reg], rm);
      float alpha = __expf(mrow[reg] - mnew);
      mrow[reg] = mnew;
      float psum = 0.f;
#pragma unroll
      for (int nb = 0; nb < 4; ++nb) {
        float p = __expf(s[nb][reg] - mnew);
        psum += p;
        Ps[(wave * 16 + quad * 4 + reg) * LSTR + nb * 16 + li] = bfbits(p);
      }
      psum += __shfl_xor(psum, 1);
      psum += __shfl_xor(psum, 2);
      psum += __shfl_xor(psum, 4);
      psum += __shfl_xor(psum, 8);
      lrow[reg] = lrow[reg] * alpha + psum;
#pragma unroll
      for (int db = 0; db < 4; ++db) accO[db][reg] *= alpha;
    }
    __syncthreads();

#pragma unroll
    for (int db = 0; db < 4; ++db)
#pragma unroll
      for (int kc = 0; kc < 2; ++kc) {
        LdsVec a, b;
        a.u = *(const uint4*)&Ps[(wave * 16 + li) * LSTR + kc * 32 + quad * 8];
        b.u = *(const uint4*)&Vts[(db * 16 + li) * LSTR + kc * 32 + quad * 8];
        accO[db] = __builtin_amdgcn_mfma_f32_16x16x32_bf16(a.v, b.v, accO[db], 0, 0, 0);
      }
  }

  int batch = bh >> 2, head = bh & 3;
  __syncthreads();
  if (tid < 128) {   // stage M_h slice [16 oi][64 hd] into Qs
    int r = tid >> 3, c8 = (tid & 7) * 8;
    *(uint4*)&Qs[r * LSTR + c8] = *(const uint4*)&Mbf[r * 256 + head * 64 + c8];
  }
#pragma unroll
  for (int reg = 0; reg < 4; ++reg) {
    float inv = 1.f / lrow[reg];
#pragma unroll
    for (int db = 0; db < 4; ++db)
      Ps[(wave * 16 + quad * 4 + reg) * LSTR + db * 16 + li] =
          bfbits(accO[db][reg] * inv);
  }
  __syncthreads();
  f32x4 pacc = (f32x4){0.f, 0.f, 0.f, 0.f};
#pragma unroll
  for (int kc = 0; kc < 2; ++kc) {
    LdsVec a, b;
    a.u = *(const uint4*)&Ps[(wave * 16 + li) * LSTR + kc * 32 + quad * 8];
    b.u = *(const uint4*)&Qs[li * LSTR + kc * 32 + quad * 8];
    pacc = __builtin_amdgcn_mfma_f32_16x16x32_bf16(a.v, b.v, pacc, 0, 0, 0);
  }
  long pbase = (long)(batch >> 2) * 32768 + (batch & 3) * 16 + li;
#pragma unroll
  for (int reg = 0; reg < 4; ++reg) {
    int t = qt * 64 + wave * 16 + quad * 4 + reg;
    atomicAdd(&P[pbase + (long)t * 64], pacc[reg] * INV2PI);  // revolutions
  }
}

// ---------------- fused scan + logits/log_softmax (16 blocks x 512) --------
// Scan: chunked block-Jacobi fixed point (R3, verified: serial depth 512->64).
// R6: k_final merged in -- after the sweeps, thread t computes its row's 64
// logits from LDS hsb + LDS-staged Wt/Bt and writes log_softmax directly.
// Removes one dispatch (+gap) and k_final's scattered scalar weight loads.
#define SWEEPS 4
#define CHUNK 16
#define NCH 32

template <bool DIRB>
__device__ __forceinline__ void scan_sweeps(
    const float* __restrict__ Pb,
    int c, int G, int w,
    float rr0, float rr1, float rr2, float rr3,
    float kk, float e1, float mkm1,
    int s0, int s1, int s2, int s3,
    float (*bH)[NCH + 1][4], float (*bC)[NCH + 1][4],
    float* __restrict__ hsb) {
  float pcv[CHUNK];
#pragma unroll
  for (int j = 0; j < CHUNK; ++j)
    pcv[j] = Pb[(long)(c * CHUNK + j) * 64];

#pragma unroll 1
  for (int s = 0; s < SWEEPS; ++s) {
    int rd = s & 1, wr = rd ^ 1;
    float h0 = bH[rd][c][0], h1 = bH[rd][c][1];
    float h2 = bH[rd][c][2], h3 = bH[rd][c][3];
    float cx = bC[rd][c][w];
    float hx = 0.f;
#pragma unroll
    for (int u = 0; u < CHUNK; ++u) {
      float pc = pcv[u];
      float d01 = __builtin_fmaf(rr1, h1, __builtin_fmaf(rr0, h0, pc));
      float d23 = __builtin_fmaf(rr3, h3, rr2 * h2);
      float a = d01 + d23;                 // revolutions
      float cth = fcosr(a);
      float c0 = dppf<0x00>(cth), c1 = dppf<0x55>(cth);
      float c2 = dppf<0xAA>(cth), c3 = dppf<0xFF>(cth);
      float p01 = c0 * c1, z23 = c2 * c3;
      float v = (w == 0) ? c1 * z23 : (w == 1) ? p01
              : (w == 2) ? p01 * c2 : p01 * z23;
      float val = __builtin_fmaf(kk, frcp(1.f + fexp2(e1 * v)), mkm1);
      float ra = dppf<0x124>(val);
      float rb = dppf<0x128>(val);
      float rc = dppf<0x12C>(val);
      float rot1 = DIRB ? ra : rc;
      float rot3 = DIRB ? rc : ra;
      float f = (s0 == 0) ? val : (s0 == 1) ? rot1 : (s0 == 2) ? rb : rot3;
      float i = (s1 == 0) ? val : (s1 == 1) ? rot1 : (s1 == 2) ? rb : rot3;
      float g = (s2 == 0) ? val : (s2 == 1) ? rot1 : (s2 == 2) ? rb : rot3;
      float o = (s3 == 0) ? val : (s3 == 1) ? rot1 : (s3 == 2) ? rb : rot3;
      cx = __builtin_fmaf(f, cx, i * g);
      float rt = frcp(1.f + fexp2(-2.88539008f * cx));
      hx = __builtin_fmaf(o + o, rt, -o);
      h0 = dppf<0x00>(hx); h1 = dppf<0x55>(hx);
      h2 = dppf<0xAA>(hx); h3 = dppf<0xFF>(hx);
      if (G == 0) hsb[(c * CHUNK + u) * 4 + w] = hx;
    }
    if (G == 0) {
      bH[wr][c + 1][w] = hx;
      bC[wr][c + 1][w] = cx;
    }
    __syncthreads();
  }
}

__global__ __launch_bounds__(512) void k_scanf(const float* __restrict__ P,
                                               const void* Wf, const void* Wi,
                                               const void* Wg, const void* Wo2,
                                               const void* Wt, const void* Bt,
                                               void* outp) {
  __shared__ float bH[2][NCH + 1][4];
  __shared__ float bC[2][NCH + 1][4];
  __shared__ __align__(16) float hsb[512 * 4];
  __shared__ float sWt[256];
  __shared__ float sBt[64];
  int tid = threadIdx.x;
  int b = blockIdx.x;            // batch 0..15
  int c = tid >> 4;              // chunk 0..31
  int l16 = tid & 15;
  int G = l16 >> 2, w = l16 & 3;
  int lane = tid & 63;

  if (tid < 2 * (NCH + 1) * 4) {
    ((float*)bH)[tid] = 0.f;
    ((float*)bC)[tid] = 0.f;
  }

  // wave-local dtype detect (identical across waves)
  const __hip_bfloat16* pw = (const __hip_bfloat16*)Wf;
  int big = 0;
  for (int i = lane; i < 1040; i += 64) {
    float v = __bfloat162float(pw[i]);
    if (fabsf(v) > 1e4f) big = 1;
  }
  int isbf = (__ballot(big) == 0ULL) ? 1 : 0;

  // stage Wt/Bt (covered by the pre-sweep barrier)
  if (tid < 256) sWt[tid] = ldf(Wt, isbf, tid);
  else if (tid < 320) sBt[tid - 256] = ldf(Bt, isbf, tid - 256);

  int got = __builtin_amdgcn_update_dpp(0, lane, 0x124, 0xF, 0xF, false); // row_ror:4
  int dir = __shfl((got == 9) ? 1 : 0, 5);
  const void* Wsel = (G == 0) ? Wf : (G == 1) ? Wi : (G == 2) ? Wg : Wo2;
  float rr0 = ldf(Wsel, isbf, (long)w * 260 + 256 + 0) * INV2PI;
  float rr1 = ldf(Wsel, isbf, (long)w * 260 + 256 + 1) * INV2PI;
  float rr2 = ldf(Wsel, isbf, (long)w * 260 + 256 + 2) * INV2PI;
  float rr3 = ldf(Wsel, isbf, (long)w * 260 + 256 + 3) * INV2PI;
  float kk = (G == 2) ? 2.f : 1.f;
  float e1 = -kk * 1.44269504f;
  float mkm1 = 1.f - kk;
  int s0 = (0 - G) & 3, s1 = (1 - G) & 3, s2 = (2 - G) & 3, s3 = (3 - G) & 3;

  const float* Pb = P + (long)(b >> 2) * 32768 + (b & 3) * 16 + l16;
  __syncthreads();  // zero-init + sWt/sBt visible

  if (dir)
    scan_sweeps<true>(Pb, c, G, w, rr0, rr1, rr2, rr3,
                      kk, e1, mkm1, s0, s1, s2, s3, bH, bC, hsb);
  else
    scan_sweeps<false>(Pb, c, G, w, rr0, rr1, rr2, rr3,
                       kk, e1, mkm1, s0, s1, s2, s3, bH, bC, hsb);
  // last sweep ends with __syncthreads -> hsb complete

  // ---- logits + log_softmax for row (b, t=tid) ----
  float h0 = hsb[tid * 4 + 0], h1 = hsb[tid * 4 + 1];
  float h2 = hsb[tid * 4 + 2], h3 = hsb[tid * 4 + 3];
  float lg[64];
  float mx = -1e30f;
#pragma unroll
  for (int j = 0; j < 64; ++j) {
    float v = sBt[j]
            + h0 * sWt[j * 4 + 0] + h1 * sWt[j * 4 + 1]
            + h2 * sWt[j * 4 + 2] + h3 * sWt[j * 4 + 3];
    lg[j] = v;
    mx = fmaxf(mx, v);
  }
  float ssum = 0.f;
#pragma unroll
  for (int j = 0; j < 64; ++j) ssum += __expf(lg[j] - mx);
  float sub = mx + __logf(ssum);
  long rbase = ((long)b * 512 + tid) * 64;
  if (isbf) {
    __hip_bfloat16* ob = (__hip_bfloat16*)outp;
#pragma unroll
    for (int j0 = 0; j0 < 8; ++j0) {
      uint4 pk;
      pk.x = pack2(lg[j0 * 8 + 0] - sub, lg[j0 * 8 + 1] - sub);
      pk.y = pack2(lg[j0 * 8 + 2] - sub, lg[j0 * 8 + 3] - sub);
      pk.z = pack2(lg[j0 * 8 + 4] - sub, lg[j0 * 8 + 5] - sub);
      pk.w = pack2(lg[j0 * 8 + 6] - sub, lg[j0 * 8 + 7] - sub);
      *(uint4*)(ob + rbase + j0 * 8) = pk;
    }
  } else {
    float* of = (float*)outp;
#pragma unroll
    for (int j0 = 0; j0 < 16; ++j0) {
      float4 v4;
      v4.x = lg[j0 * 4 + 0] - sub; v4.y = lg[j0 * 4 + 1] - sub;
      v4.z = lg[j0 * 4 + 2] - sub; v4.w = lg[j0 * 4 + 3] - sub;
      *(float4*)(of + rbase + j0 * 4) = v4;
    }
  }
}

extern "C" void kernel_launch(void* const* d_in, const int* in_sizes, int n_in,
                              void* d_out, int out_size, void* d_ws, size_t ws_size,
                              hipStream_t stream) {
  const int* sent = (const int*)d_in[0];
  const void* emb = d_in[1];
  const void* Wq = d_in[2];  const void* bq = d_in[3];
  const void* Wk = d_in[4];  const void* bk = d_in[5];
  const void* Wv = d_in[6];  const void* bv = d_in[7];
  const void* Wo = d_in[8];  const void* bo = d_in[9];
  const void* Wf = d_in[10]; const void* bF = d_in[11]; const void* thF = d_in[12];
  const void* Wi = d_in[13]; const void* bI = d_in[14]; const void* thI = d_in[15];
  const void* Wg = d_in[16]; const void* bG = d_in[17]; const void* thG = d_in[18];
  const void* Wo2 = d_in[19]; const void* bO = d_in[20]; const void* thO = d_in[21];
  const void* Wt = d_in[22]; const void* Bt = d_in[23];

  float* base = (float*)((char*)d_ws + 256);
  __hip_bfloat16* Mbf = (__hip_bfloat16*)base;                 // 16x256 bf16
  __hip_bfloat16* Qbf  = (__hip_bfloat16*)(base + 4096);       // 4MB
  __hip_bfloat16* Kbf  = (__hip_bfloat16*)(base + 4096 + 1048576);
  __hip_bfloat16* Vtbf = (__hip_bfloat16*)(base + 4096 + 2097152);
  float* Pp = base + 4096 + 3145728;   // 131072 f32 (4 x 32768 block-major)

  dim3 gq(128, 1, 4);
  k_qkvc<<<gq, 256, 0, stream>>>(sent, emb, Wq, Wk, Wv, bq, bk, bv, Wo, bo,
                                 Wf, Wi, Wg, Wo2, bF, bI, bG, bO,
                                 thF, thI, thG, thO, Qbf, Kbf, Vtbf, Mbf, Pp);
  dim3 ga(64, 8, 1);
  k_attn<<<ga, 256, 0, stream>>>(Qbf, Kbf, Vtbf, Mbf, Pp);
  k_scanf<<<16, 512, 0, stream>>>(Pp, Wf, Wi, Wg, Wo2, Wt, Bt, d_out);
}